// Round 2
// baseline (549.317 us; speedup 1.0000x reference)
//
#include <hip/hip_runtime.h>

// Problem constants
constexpr int NB   = 2;
constexpr int CIN  = 128;
constexpr int TT   = 8;
constexpr int HH   = 56;
constexpr int WW   = 56;
constexpr int S    = TT * HH * WW;      // 25088 positions per batch
constexpr int DK   = 16;
constexpr int DV   = 128;
constexpr int TAPS = 147;               // 3*7*7
// Padded v layout: [b][c][t+2pad=10][h+6pad=62][w+6pad=62]
constexpr int VPT  = 10, VPH = 62, VPW = 62;
constexpr int PLANE = VPH * VPW;        // 3844
constexpr int SPAD  = VPT * PLANE;      // 38440
constexpr float EPSf = 1e-6f;

// ---------------------------------------------------------------------------
// Kernel 1: projection + q-norm + v (unscaled) into padded layout + 1/||v||.
// One thread per (b,p). 4 independent FMA chains (grid is tiny: 784 waves on
// 1024 SIMDs -> single-wave dep-latency was the floor).
// ---------------------------------------------------------------------------
__global__ __launch_bounds__(64) void k_proj(
    const float* __restrict__ x, const float* __restrict__ Wp,
    float* __restrict__ qn, float* __restrict__ vpad, float* __restrict__ invv)
{
    int gid = blockIdx.x * 64 + threadIdx.x;      // < NB*S
    int b = gid / S, p = gid - b * S;
    const float* xb = x + (size_t)b * CIN * S + p;

    float xr[CIN];
#pragma unroll
    for (int c = 0; c < CIN; ++c) xr[c] = xb[(size_t)c * S];

    int t  = p / (HH * WW);
    int hw = p - t * (HH * WW);
    int h  = hw / WW;
    int w  = hw - h * WW;
    size_t padpos = (size_t)(t + 1) * PLANE + (size_t)(h + 3) * VPW + (w + 3);

    // q channels 0..15 (normalized over the 16-channel group)
    float qv[DK];
    float ssq = 0.f;
#pragma unroll 1
    for (int o = 0; o < DK; o += 4) {
        const float* wp0 = Wp + (size_t)o * CIN;
        float a0 = 0.f, a1 = 0.f, a2 = 0.f, a3 = 0.f;
#pragma unroll
        for (int c = 0; c < CIN; ++c) {
            float xc = xr[c];
            a0 = fmaf(wp0[c],           xc, a0);
            a1 = fmaf(wp0[CIN + c],     xc, a1);
            a2 = fmaf(wp0[2 * CIN + c], xc, a2);
            a3 = fmaf(wp0[3 * CIN + c], xc, a3);
        }
        qv[o] = a0; qv[o + 1] = a1; qv[o + 2] = a2; qv[o + 3] = a3;
        ssq += a0 * a0 + a1 * a1 + a2 * a2 + a3 * a3;
    }
    float qs = 1.0f / sqrtf(ssq + EPSf);
#pragma unroll
    for (int o = 0; o < DK; ++o)
        qn[((size_t)b * DK + o) * S + p] = qv[o] * qs;

    // v channels: write unscaled into padded layout, accumulate sumsq
    float ssv = 0.f;
#pragma unroll 1
    for (int o = 0; o < DV; o += 4) {
        const float* wp0 = Wp + (size_t)(DK + o) * CIN;
        float a0 = 0.f, a1 = 0.f, a2 = 0.f, a3 = 0.f;
#pragma unroll
        for (int c = 0; c < CIN; ++c) {
            float xc = xr[c];
            a0 = fmaf(wp0[c],           xc, a0);
            a1 = fmaf(wp0[CIN + c],     xc, a1);
            a2 = fmaf(wp0[2 * CIN + c], xc, a2);
            a3 = fmaf(wp0[3 * CIN + c], xc, a3);
        }
        ssv += a0 * a0 + a1 * a1 + a2 * a2 + a3 * a3;
        float* vdst = vpad + (size_t)(b * DV + o) * SPAD + padpos;
        vdst[0]              = a0;
        vdst[(size_t)SPAD]   = a1;
        vdst[(size_t)2*SPAD] = a2;
        vdst[(size_t)3*SPAD] = a3;
    }
    invv[gid] = 1.0f / sqrtf(ssv + EPSf);
}

// ---------------------------------------------------------------------------
// Kernel 2: scale v in place (padded layout) by per-position inv norm.
// ---------------------------------------------------------------------------
__global__ __launch_bounds__(256) void k_scale(
    float* __restrict__ vpad, const float* __restrict__ invv)
{
    int gid = blockIdx.x * 256 + threadIdx.x;     // < NB*DV*S
    int b = gid / (DV * S);
    int r = gid - b * (DV * S);
    int c = r / S;
    int p = r - c * S;
    int t  = p / (HH * WW);
    int hw = p - t * (HH * WW);
    int h  = hw / WW;
    int w  = hw - h * WW;
    size_t a = (size_t)(b * DV + c) * SPAD
             + (size_t)(t + 1) * PLANE + (size_t)(h + 3) * VPW + (w + 3);
    vpad[a] *= invv[b * S + p];
}

// ---------------------------------------------------------------------------
// Kernel 3 (fused): per-(b,t,h)-row block.
//   Phase 1: weff[tap][w] = sum_k q[k,w]*W_H2[k,tap] into LDS (once per row,
//            shared by all 128 channels -> kills the weff HBM round-trip).
//   Phase 2: out[c][w] = sum_tap weff[tap][w] * vpad[c][neighbor] — padded v,
//            branchless taps, two overlapping dwordx4 per 7-tap row.
// Thread map: w = tid%56, grp = tid/56 (4 groups x 32 channels; 32 lanes idle).
// ---------------------------------------------------------------------------
__global__ __launch_bounds__(256) void k_out(
    const float* __restrict__ vpad, const float* __restrict__ qn,
    const float* __restrict__ wh2, float* __restrict__ out)
{
    __shared__ float wh2_s[DK * TAPS];   // 9.4 KB
    __shared__ float q_s[DK * 56];       // 3.6 KB
    __shared__ float weff_s[TAPS * 56];  // 32.9 KB

    // chunked XCD swizzle: 896 blocks, each XCD owns 112 contiguous (b,t,h)
    int bid = blockIdx.x;
    int nid = (bid & 7) * 112 + (bid >> 3);
    int h = nid % 56;
    int t = (nid / 56) & 7;
    int b = nid / 448;
    int tid = threadIdx.x;
    int pbase = t * (HH * WW) + h * WW;

    for (int i = tid; i < DK * TAPS; i += 256) wh2_s[i] = wh2[i];
    for (int i = tid; i < DK * 56; i += 256) {
        int k = i / 56, w = i - k * 56;
        q_s[i] = qn[((size_t)b * DK + k) * S + pbase + w];
    }
    __syncthreads();

    int w   = tid % 56;
    int grp = tid / 56;          // 0..3 active, 4 = idle tail
    bool act = grp < 4;

    if (act) {
        float qr[DK];
#pragma unroll
        for (int k = 0; k < DK; ++k) qr[k] = q_s[k * 56 + w];
#pragma unroll 1
        for (int tap = grp; tap < TAPS; tap += 4) {
            float a = 0.f;
#pragma unroll
            for (int k = 0; k < DK; ++k)
                a = fmaf(qr[k], wh2_s[k * TAPS + tap], a);
            weff_s[tap * 56 + w] = a;
        }
    }
    __syncthreads();

    if (!act) return;

    const float* vb = vpad + (size_t)(b * DV + grp * 32) * SPAD;
    float acc[32];
#pragma unroll
    for (int j = 0; j < 32; ++j) acc[j] = 0.f;

#pragma unroll 1
    for (int dz = 0; dz < 3; ++dz) {
#pragma unroll 1
        for (int dy = 0; dy < 7; ++dy) {
            int tapb = (dz * 7 + dy) * 7;
            float wr[7];
#pragma unroll
            for (int dx = 0; dx < 7; ++dx)
                wr[dx] = weff_s[(tapb + dx) * 56 + w];
            const float* rp = vb + (size_t)(t + dz) * PLANE
                                 + (size_t)(h + dy) * VPW + w;
#pragma unroll 8
            for (int j = 0; j < 32; ++j) {
                float4 A, B;
                __builtin_memcpy(&A, rp, 16);       // taps dx=0..3
                __builtin_memcpy(&B, rp + 4, 16);   // taps dx=4..6 (+1 slack)
                float s = fmaf(wr[0], A.x,
                          fmaf(wr[1], A.y,
                          fmaf(wr[2], A.z,
                          fmaf(wr[3], A.w,
                          fmaf(wr[4], B.x,
                          fmaf(wr[5], B.y, wr[6] * B.z))))));
                acc[j] += s;
                rp += SPAD;
            }
        }
    }

    size_t ob = ((size_t)b * DV + grp * 32) * S + pbase + w;
#pragma unroll
    for (int j = 0; j < 32; ++j)
        out[ob + (size_t)j * S] = acc[j];
}

// ---------------------------------------------------------------------------
extern "C" void kernel_launch(void* const* d_in, const int* in_sizes, int n_in,
                              void* d_out, int out_size, void* d_ws, size_t ws_size,
                              hipStream_t stream)
{
    const float* x   = (const float*)d_in[0];   // (2,128,8,56,56)
    const float* Wp  = (const float*)d_in[1];   // (144,128)
    const float* wh2 = (const float*)d_in[2];   // (16,1,3,7,7) -> [k][147]
    float* out = (float*)d_out;                 // (2,128,8,56,56)

    float* ws   = (float*)d_ws;
    float* qn   = ws;                               // NB*DK*S     =   802,816
    float* invv = qn   + (size_t)NB * DK * S;       // NB*S        =    50,176
    float* vpad = invv + (size_t)NB * S;            // NB*DV*SPAD  = 9,840,640 (+slack)

    hipMemsetAsync(vpad, 0, (size_t)NB * DV * SPAD * sizeof(float) + 64, stream);
    k_proj <<<dim3(NB * S / 64), dim3(64),  0, stream>>>(x, Wp, qn, vpad, invv);
    k_scale<<<dim3(NB * DV * S / 256), dim3(256), 0, stream>>>(vpad, invv);
    k_out  <<<dim3(NB * TT * HH), dim3(256), 0, stream>>>(vpad, qn, wh2, out);
}

// Round 3
// 151.313 us; speedup vs baseline: 3.6303x; 3.6303x over previous
//
#include <hip/hip_runtime.h>

constexpr int NB   = 2;
constexpr int CIN  = 128;
constexpr int TT   = 8;
constexpr int HH   = 56;
constexpr int WW   = 56;
constexpr int S    = TT * HH * WW;      // 25088
constexpr int DK   = 16;
constexpr int DV   = 128;
constexpr int TAPS = 147;               // 3*7*7
constexpr int NOUT = DK + DV;           // 144
// padded channel-last v: [b][t:10][h:62][w:62][c:128]
constexpr int VPT = 10, VPH = 62, VPW = 62;
constexpr float EPSf = 1e-6f;

// ---------------------------------------------------------------------------
// Wp[o][c] -> Wpt[c][144]  (so k_proj's weight reads are contiguous s_loads)
// ---------------------------------------------------------------------------
__global__ __launch_bounds__(256) void k_twp(
    const float* __restrict__ Wp, float* __restrict__ Wpt)
{
    int i = blockIdx.x * 256 + threadIdx.x;
    if (i >= CIN * NOUT) return;
    int c = i / NOUT, o = i - c * NOUT;
    Wpt[i] = Wp[o * CIN + c];
}

// ---------------------------------------------------------------------------
// k_proj: block = 256 thr = 4 waves; each wave = same 64 positions, one
// 36-channel quarter. x tile shared via L1 (4 waves hit same lines).
// ssv reduced across quarters in LDS; v scaled in-register, written once
// (channel-last padded layout). q normalized+written by quarter 0.
// ---------------------------------------------------------------------------
__global__ __launch_bounds__(256) void k_proj(
    const float* __restrict__ x, const float* __restrict__ Wpt,
    float* __restrict__ qn, float* __restrict__ vcl)
{
    __shared__ float svl[4 * 64];
    int tid = threadIdx.x;
    int pos = tid & 63;
    int og  = __builtin_amdgcn_readfirstlane(tid >> 6);  // wave-uniform scalar
    int gid = blockIdx.x * 64 + pos;                     // < NB*S
    int b = gid / S, p = gid - b * S;

    const float* xp = x + (size_t)b * CIN * S + p;
    const float* wr = Wpt + og * 36;

    float acc[36];
#pragma unroll
    for (int o = 0; o < 36; ++o) acc[o] = 0.f;

#pragma unroll 2
    for (int c = 0; c < CIN; ++c) {
        float xc = xp[(size_t)c * S];
#pragma unroll
        for (int o = 0; o < 36; ++o)
            acc[o] = fmaf(xc, wr[c * NOUT + o], acc[o]);
    }

    float s_all = 0.f;
#pragma unroll
    for (int o = 0; o < 36; ++o) s_all += acc[o] * acc[o];
    float ssq = 0.f;
    if (og == 0) {
#pragma unroll
        for (int o = 0; o < 16; ++o) ssq += acc[o] * acc[o];
    }
    svl[og * 64 + pos] = s_all - ssq;   // v-part of this quarter
    __syncthreads();
    float ssv = svl[pos] + svl[64 + pos] + svl[128 + pos] + svl[192 + pos];
    float vsc = 1.0f / sqrtf(ssv + EPSf);

    if (og == 0) {
        float qsc = 1.0f / sqrtf(ssq + EPSf);
#pragma unroll
        for (int o = 0; o < DK; ++o)
            qn[((size_t)b * DK + o) * S + p] = acc[o] * qsc;
    }

    int t  = p / (HH * WW);
    int hw = p - t * (HH * WW);
    int h  = hw / WW;
    int w  = hw - h * WW;
    float* vd = vcl + (((size_t)(b * VPT + t + 1) * VPH + (h + 3)) * VPW + (w + 3)) * 128;

    if (og == 0) {
        // v channels 0..19 from acc[16..35]
#pragma unroll
        for (int j = 0; j < 20; j += 4) {
            float4 v4 = {acc[16 + j] * vsc, acc[17 + j] * vsc,
                         acc[18 + j] * vsc, acc[19 + j] * vsc};
            *reinterpret_cast<float4*>(vd + j) = v4;
        }
    } else {
        vd += og * 36 - 16;             // v channels og*36-16 .. +35
#pragma unroll
        for (int j = 0; j < 36; j += 4) {
            float4 v4 = {acc[j] * vsc, acc[j + 1] * vsc,
                         acc[j + 2] * vsc, acc[j + 3] * vsc};
            *reinterpret_cast<float4*>(vd + j) = v4;
        }
    }
}

// ---------------------------------------------------------------------------
// k_out: block = (b,t,h) row, 128 threads = 2 waves.
//   Phase 1: q row -> LDS.
//   Phase 2: weff[w][tap] into LDS (tap-parity split across 2 half-groups).
//   Phase 3: thread = (cc: 8 channels, wt: 7 outputs). Sliding window over
//            13 padded cols per (dz,dy) row: each 32B v load feeds up to
//            56 FMAs; weff read as conflict-free LDS broadcast.
// ---------------------------------------------------------------------------
__global__ __launch_bounds__(128) void k_out(
    const float* __restrict__ vcl, const float* __restrict__ qn,
    const float* __restrict__ wh2, float* __restrict__ out)
{
    __shared__ float q_s[DK * WW];       // 3.5 KB
    __shared__ float weff[WW * 148];     // 33.2 KB  (148: bank-spread stride)

    int tid = threadIdx.x;
    // XCD-chunked swizzle: 896 = 8 * 112
    int bid = blockIdx.x;
    int nid = (bid & 7) * 112 + (bid >> 3);
    int b   = nid / 448;
    int rem = nid - b * 448;
    int t   = rem / 56, h = rem - t * 56;
    int pbase = t * (HH * WW) + h * WW;

    for (int i = tid; i < DK * WW; i += 128) {
        int k = i / 56, w = i - k * 56;
        q_s[i] = qn[((size_t)b * DK + k) * S + pbase + w];
    }
    __syncthreads();

    {
        int w = tid % 56, half = tid / 56;
        if (half < 2) {
            float qr[DK];
#pragma unroll
            for (int k = 0; k < DK; ++k) qr[k] = q_s[k * 56 + w];
            for (int tap = half; tap < TAPS; tap += 2) {
                float a = 0.f;
#pragma unroll
                for (int k = 0; k < DK; ++k)
                    a = fmaf(qr[k], wh2[k * TAPS + tap], a);
                weff[w * 148 + tap] = a;
            }
        }
    }
    __syncthreads();

    int cc = tid & 15;       // 16 chunks x 8 channels = 128
    int wt = tid >> 4;       // 8 tiles x 7 outputs   = 56
    int wbase = wt * 7;

    const float* vbase = vcl
        + ((size_t)(b * VPT + t) * VPH + h) * VPW * 128   // padded (t,h) origin
        + (size_t)wbase * 128 + cc * 8;

    float acc[7][8];
#pragma unroll
    for (int k = 0; k < 7; ++k)
#pragma unroll
        for (int j = 0; j < 8; ++j) acc[k][j] = 0.f;

#pragma unroll 1
    for (int dz = 0; dz < 3; ++dz) {
#pragma unroll 1
        for (int dy = 0; dy < 7; ++dy) {
            const float* vr = vbase + (size_t)((dz * VPH + dy) * VPW) * 128;
            int tapb = (dz * 7 + dy) * 7;
            const float* wrow = &weff[wbase * 148 + tapb];
#pragma unroll
            for (int j = 0; j < 13; ++j) {
                float4 A = *reinterpret_cast<const float4*>(vr + j * 128);
                float4 B = *reinterpret_cast<const float4*>(vr + j * 128 + 4);
                constexpr int seven = 7;
                int k0 = (j - 6 > 0) ? (j - 6) : 0;
                int k1 = (j < 6) ? j : 6;
#pragma unroll
                for (int k = 0; k < seven; ++k) {
                    if (k < k0 || k > k1) continue;      // compile-time pruned
                    float wv = wrow[k * 148 + (j - k)];
                    acc[k][0] = fmaf(wv, A.x, acc[k][0]);
                    acc[k][1] = fmaf(wv, A.y, acc[k][1]);
                    acc[k][2] = fmaf(wv, A.z, acc[k][2]);
                    acc[k][3] = fmaf(wv, A.w, acc[k][3]);
                    acc[k][4] = fmaf(wv, B.x, acc[k][4]);
                    acc[k][5] = fmaf(wv, B.y, acc[k][5]);
                    acc[k][6] = fmaf(wv, B.z, acc[k][6]);
                    acc[k][7] = fmaf(wv, B.w, acc[k][7]);
                }
            }
        }
    }

    size_t ob = ((size_t)b * DV + cc * 8) * S + pbase + wbase;
#pragma unroll
    for (int j = 0; j < 8; ++j)
#pragma unroll
        for (int k = 0; k < 7; ++k)
            out[ob + (size_t)j * S + k] = acc[k][j];
}

// ---------------------------------------------------------------------------
extern "C" void kernel_launch(void* const* d_in, const int* in_sizes, int n_in,
                              void* d_out, int out_size, void* d_ws, size_t ws_size,
                              hipStream_t stream)
{
    const float* x   = (const float*)d_in[0];   // (2,128,8,56,56)
    const float* Wp  = (const float*)d_in[1];   // (144,128)
    const float* wh2 = (const float*)d_in[2];   // (16,1,3,7,7) -> [k][147]
    float* out = (float*)d_out;                 // (2,128,8,56,56)

    float* ws  = (float*)d_ws;
    float* Wpt = ws;                                   //      18,432 floats
    float* qn  = Wpt + (size_t)CIN * NOUT;             //     802,816 floats
    float* vcl = qn  + (size_t)NB * DK * S;            //   9,840,640 floats

    size_t vcl_bytes = (size_t)NB * VPT * VPH * VPW * 128 * sizeof(float);

    k_twp<<<dim3((CIN * NOUT + 255) / 256), dim3(256), 0, stream>>>(Wp, Wpt);
    hipMemsetAsync(vcl, 0, vcl_bytes, stream);
    k_proj<<<dim3(NB * S / 64), dim3(256), 0, stream>>>(x, Wpt, qn, vcl);
    k_out <<<dim3(NB * TT * HH), dim3(128), 0, stream>>>(vcl, qn, wh2, out);
}